// Round 2
// baseline (384.149 us; speedup 1.0000x reference)
//
#include <hip/hip_runtime.h>

typedef float f32x2 __attribute__((ext_vector_type(2)));

#define IMG_W 512
#define IMG_H 512
#define TY 8
#define PLANES 96              // N*C = 32*3
#define NPIX (32ll * 3 * 512 * 512)

// Separable Gaussian, sigma=1.5, size=11, normalized (compile-time folded).
#define WG_INIT { 0.00102838f, 0.00759876f, 0.03600077f, 0.10936069f, \
                  0.21300553f, 0.26601172f, 0.21300553f, 0.10936069f, \
                  0.03600077f, 0.00759876f, 0.00102838f }

__global__ __launch_bounds__(512, 4)
void ssim_main(const float* __restrict__ pred, const float* __restrict__ targ,
               double* __restrict__ acc) {
    const float WG[11] = WG_INIT;

    // 5 maps x 2 row-pair slots x (8 pad | 512 data | 8 pad) cols x 2 rows-in-pair
    // float2-interleaved so horizontal taps are packed across the row pair.
    __shared__ __align__(16) float lds[5][2][528 * 2];
    __shared__ float wsum[8];

    const int tid   = threadIdx.x;
    const int x     = tid;                 // column owned in vertical pass
    const int plane = blockIdx.y;
    const int y0    = blockIdx.x * TY;
    const size_t base = (size_t)plane * (IMG_W * IMG_H);
    const float* pCol = pred + base + x;
    const float* tCol = targ + base + x;

    // Zero horizontal halo pads once (data writes never touch them, so they
    // stay zero across both halves).
    if (tid < 160) {
        int m   = tid >> 5;           // 0..4
        int rem = tid & 31;
        int rl  = rem >> 4;           // 0..1
        int cc  = rem & 15;           // 0..15
        int c   = (cc < 8) ? cc : (512 + cc);
        *(f32x2*)&lds[m][rl][2 * c] = (f32x2){0.f, 0.f};
    }

    // ---- vertical pass: packed over row pairs (2rp, 2rp+1) ----
    f32x2 A[5][4];
#pragma unroll
    for (int m = 0; m < 5; ++m)
#pragma unroll
        for (int rp = 0; rp < 4; ++rp) A[m][rp] = (f32x2){0.f, 0.f};

#pragma unroll
    for (int iy = 0; iy < TY + 10; ++iy) {
        int y = y0 - 5 + iy;
        float p = 0.f, t = 0.f;
        if ((unsigned)y < (unsigned)IMG_H) {   // wave-uniform
            p = pCol[(size_t)y * IMG_W];
            t = tCol[(size_t)y * IMG_W];
        }
        f32x2 vs[5];
        vs[0] = (f32x2){p, p};
        vs[1] = (f32x2){t, t};
        float pp = p * p, tt = t * t, pt = p * t;
        vs[2] = (f32x2){pp, pp};
        vs[3] = (f32x2){tt, tt};
        vs[4] = (f32x2){pt, pt};
#pragma unroll
        for (int rp = 0; rp < 4; ++rp) {
            const int a = iy - 2 * rp;         // compile-time
            if (a < 0 || a > 11) continue;     // both weight lanes zero
            const float w0 = (a <= 10) ? WG[a] : 0.f;       // row 2rp
            const float w1 = (a >= 1) ? WG[a - 1] : 0.f;    // row 2rp+1
            const f32x2 w = (f32x2){w0, w1};
#pragma unroll
            for (int m = 0; m < 5; ++m)
                A[m][rp] = __builtin_elementwise_fma(vs[m], w, A[m][rp]);
        }
    }

    // ---- horizontal pass + SSIM, two 4-row halves through LDS ----
    const float C1 = 1e-4f, C2 = 9e-4f;
    float lsum = 0.f;
    const int rpl = tid >> 8;          // 0..1: which row pair this thread reads
    const int xq  = (tid & 255) * 2;   // first of 2 output cols (even)

#pragma unroll
    for (int half = 0; half < 2; ++half) {
        __syncthreads();   // pads ready (1st) / previous chunk consumed (2nd)
#pragma unroll
        for (int m = 0; m < 5; ++m)
#pragma unroll
            for (int rl = 0; rl < 2; ++rl)
                *(f32x2*)&lds[m][rl][2 * (x + 8)] = A[m][2 * half + rl];
        __syncthreads();

        // out col j taps stored entries j+3..j+13; cols (xq, xq+1) need
        // entries xq+3..xq+14; read aligned window xq+2..xq+15 (7 x b128).
        f32x2 H[5][2];
#pragma unroll
        for (int m = 0; m < 5; ++m) {
            f32x2 win[14];
#pragma unroll
            for (int q = 0; q < 7; ++q) {
                const float4 v = *(const float4*)&lds[m][rpl][2 * (xq + 2) + 4 * q];
                win[2 * q]     = (f32x2){v.x, v.y};
                win[2 * q + 1] = (f32x2){v.z, v.w};
            }
            f32x2 h0 = (f32x2){0.f, 0.f}, h1 = (f32x2){0.f, 0.f};
#pragma unroll
            for (int k = 0; k < 11; ++k) {
                const f32x2 wk = (f32x2){WG[k], WG[k]};
                h0 = __builtin_elementwise_fma(win[1 + k], wk, h0);
                h1 = __builtin_elementwise_fma(win[2 + k], wk, h1);
            }
            H[m][0] = h0; H[m][1] = h1;
        }

#pragma unroll
        for (int c = 0; c < 2; ++c) {
            f32x2 mu1 = H[0][c], mu2 = H[1][c];
            f32x2 mu1s = mu1 * mu1, mu2s = mu2 * mu2, mu12 = mu1 * mu2;
            f32x2 s1  = H[2][c] - mu1s;
            f32x2 s2  = H[3][c] - mu2s;
            f32x2 s12 = H[4][c] - mu12;
            f32x2 num = (mu12 + mu12 + (f32x2){C1, C1}) *
                        (s12 + s12 + (f32x2){C2, C2});
            f32x2 den = (mu1s + mu2s + (f32x2){C1, C1}) *
                        (s1 + s2 + (f32x2){C2, C2}) + (f32x2){1e-8f, 1e-8f};
            lsum += num.x * __builtin_amdgcn_rcpf(den.x);
            lsum += num.y * __builtin_amdgcn_rcpf(den.y);
        }
    }

    // ---- reduction: wave shuffle -> LDS -> one double atomic per block ----
#pragma unroll
    for (int off = 32; off > 0; off >>= 1)
        lsum += __shfl_down(lsum, off);
    if ((tid & 63) == 0) wsum[tid >> 6] = lsum;
    __syncthreads();
    if (tid == 0) {
        float s = 0.f;
#pragma unroll
        for (int i = 0; i < 8; ++i) s += wsum[i];
        atomicAdd(acc, (double)s);
    }
}

__global__ void ssim_final(const double* __restrict__ acc, float* __restrict__ out) {
    out[0] = 1.0f - (float)(acc[0] * (1.0 / (double)NPIX));
}

extern "C" void kernel_launch(void* const* d_in, const int* in_sizes, int n_in,
                              void* d_out, int out_size, void* d_ws, size_t ws_size,
                              hipStream_t stream) {
    const float* pred = (const float*)d_in[0];
    const float* targ = (const float*)d_in[1];
    double* acc = (double*)d_ws;

    hipMemsetAsync(acc, 0, sizeof(double), stream);

    dim3 grid(IMG_H / TY, PLANES);   // adjacent strips -> halo L2 reuse
    ssim_main<<<grid, 512, 0, stream>>>(pred, targ, acc);
    ssim_final<<<1, 1, 0, stream>>>(acc, (float*)d_out);
}

// Round 3
// 356.175 us; speedup vs baseline: 1.0785x; 1.0785x over previous
//
#include <hip/hip_runtime.h>

typedef float f32x2 __attribute__((ext_vector_type(2)));

#define IMG_W 512
#define IMG_H 512
#define TY 4
#define PLANES 96              // N*C = 32*3
#define NPIX (32ll * 3 * 512 * 512)

// Separable Gaussian, sigma=1.5, size=11, normalized (compile-time folded).
#define WG_INIT { 0.00102838f, 0.00759876f, 0.03600077f, 0.10936069f, \
                  0.21300553f, 0.26601172f, 0.21300553f, 0.10936069f, \
                  0.03600077f, 0.00759876f, 0.00102838f }

__global__ __launch_bounds__(512, 2)
void ssim_main(const float* __restrict__ pred, const float* __restrict__ targ,
               double* __restrict__ acc) {
    const float WG[11] = WG_INIT;

    // 5 maps x 2 row-pair slots x (8 pad | 512 data | 8 pad) cols x 2 rows/pair
    // float2-interleaved: horizontal taps are packed across the row pair.
    __shared__ __align__(16) float lds[5][2][528 * 2];
    __shared__ float wsum[8];

    const int tid   = threadIdx.x;
    const int x     = tid;                 // column owned in vertical pass
    const int plane = blockIdx.y;
    const int y0    = blockIdx.x * TY;
    const size_t base = (size_t)plane * (IMG_W * IMG_H);
    const float* pCol = pred + base + x;
    const float* tCol = targ + base + x;

    // Zero horizontal halo pads (cols 0..7 and 520..527); data writes never
    // touch them. Single phase -> single barrier covers both pad+data writes.
    if (tid < 160) {
        int m   = tid >> 5;           // 0..4
        int rem = tid & 31;
        int rl  = rem >> 4;           // 0..1
        int cc  = rem & 15;           // 0..15
        int c   = (cc < 8) ? cc : (512 + cc);
        *(f32x2*)&lds[m][rl][2 * c] = (f32x2){0.f, 0.f};
    }

    // ---- vertical pass: 14 input rows -> 4 output rows as 2 packed pairs ----
    // A dies right after the LDS write: no cross-phase register liveness.
    f32x2 A[5][2];
#pragma unroll
    for (int m = 0; m < 5; ++m) { A[m][0] = (f32x2){0.f, 0.f}; A[m][1] = (f32x2){0.f, 0.f}; }

#pragma unroll
    for (int iy = 0; iy < TY + 10; ++iy) {
        int y = y0 - 5 + iy;
        float p = 0.f, t = 0.f;
        if ((unsigned)y < (unsigned)IMG_H) {   // wave-uniform
            p = pCol[(size_t)y * IMG_W];
            t = tCol[(size_t)y * IMG_W];
        }
        float pp = p * p, tt = t * t, pt = p * t;
        f32x2 vs[5] = { {p, p}, {t, t}, {pp, pp}, {tt, tt}, {pt, pt} };
#pragma unroll
        for (int rp = 0; rp < 2; ++rp) {
            const int a = iy - 2 * rp;                      // compile-time
            if (a < 0 || a > 11) continue;                  // both lanes zero
            const float w0 = (a <= 10) ? WG[a] : 0.f;       // row 2rp
            const float w1 = (a >= 1)  ? WG[a - 1] : 0.f;   // row 2rp+1
            const f32x2 w = (f32x2){w0, w1};
#pragma unroll
            for (int m = 0; m < 5; ++m)
                A[m][rp] = __builtin_elementwise_fma(vs[m], w, A[m][rp]);
        }
    }

#pragma unroll
    for (int m = 0; m < 5; ++m) {
        *(f32x2*)&lds[m][0][2 * (x + 8)] = A[m][0];
        *(f32x2*)&lds[m][1][2 * (x + 8)] = A[m][1];
    }
    __syncthreads();

    // ---- horizontal pass + SSIM ----
    const float C1 = 1e-4f, C2 = 9e-4f;
    float lsum = 0.f;
    const int rpl = tid >> 8;          // 0..1: row pair this thread processes
    const int xq  = (tid & 255) * 2;   // first of 2 output cols (even)

    // out col j taps stored entries j+3..j+13; cols (xq, xq+1) need entries
    // xq+3..xq+14; read aligned window xq+2..xq+15 (7 x ds_read_b128).
    f32x2 H[5][2];
#pragma unroll
    for (int m = 0; m < 5; ++m) {
        f32x2 win[14];
#pragma unroll
        for (int q = 0; q < 7; ++q) {
            const float4 v = *(const float4*)&lds[m][rpl][2 * (xq + 2) + 4 * q];
            win[2 * q]     = (f32x2){v.x, v.y};
            win[2 * q + 1] = (f32x2){v.z, v.w};
        }
        f32x2 h0 = (f32x2){0.f, 0.f}, h1 = (f32x2){0.f, 0.f};
#pragma unroll
        for (int k = 0; k < 11; ++k) {
            const f32x2 wk = (f32x2){WG[k], WG[k]};
            h0 = __builtin_elementwise_fma(win[1 + k], wk, h0);
            h1 = __builtin_elementwise_fma(win[2 + k], wk, h1);
        }
        H[m][0] = h0; H[m][1] = h1;
    }

#pragma unroll
    for (int c = 0; c < 2; ++c) {
        f32x2 mu1 = H[0][c], mu2 = H[1][c];
        f32x2 mu1s = mu1 * mu1, mu2s = mu2 * mu2, mu12 = mu1 * mu2;
        f32x2 s1  = H[2][c] - mu1s;
        f32x2 s2  = H[3][c] - mu2s;
        f32x2 s12 = H[4][c] - mu12;
        f32x2 num = (mu12 + mu12 + (f32x2){C1, C1}) *
                    (s12 + s12 + (f32x2){C2, C2});
        f32x2 den = (mu1s + mu2s + (f32x2){C1, C1}) *
                    (s1 + s2 + (f32x2){C2, C2}) + (f32x2){1e-8f, 1e-8f};
        lsum += num.x * __builtin_amdgcn_rcpf(den.x);
        lsum += num.y * __builtin_amdgcn_rcpf(den.y);
    }

    // ---- reduction: wave shuffle -> LDS -> one double atomic per block ----
#pragma unroll
    for (int off = 32; off > 0; off >>= 1)
        lsum += __shfl_down(lsum, off);
    if ((tid & 63) == 0) wsum[tid >> 6] = lsum;
    __syncthreads();
    if (tid == 0) {
        float s = 0.f;
#pragma unroll
        for (int i = 0; i < 8; ++i) s += wsum[i];
        atomicAdd(acc, (double)s);
    }
}

__global__ void ssim_final(const double* __restrict__ acc, float* __restrict__ out) {
    out[0] = 1.0f - (float)(acc[0] * (1.0 / (double)NPIX));
}

extern "C" void kernel_launch(void* const* d_in, const int* in_sizes, int n_in,
                              void* d_out, int out_size, void* d_ws, size_t ws_size,
                              hipStream_t stream) {
    const float* pred = (const float*)d_in[0];
    const float* targ = (const float*)d_in[1];
    double* acc = (double*)d_ws;

    hipMemsetAsync(acc, 0, sizeof(double), stream);

    dim3 grid(IMG_H / TY, PLANES);   // adjacent strips -> halo L2/L3 reuse
    ssim_main<<<grid, 512, 0, stream>>>(pred, targ, acc);
    ssim_final<<<1, 1, 0, stream>>>(acc, (float*)d_out);
}

// Round 4
// 326.494 us; speedup vs baseline: 1.1766x; 1.0909x over previous
//
#include <hip/hip_runtime.h>

typedef float f32x2 __attribute__((ext_vector_type(2)));

#define IMG_W 512
#define IMG_H 512
#define TY 4
#define PLANES 96              // N*C = 32*3
#define NPIX (32ll * 3 * 512 * 512)

// Separable Gaussian, sigma=1.5, size=11, normalized (compile-time folded).
#define WG_INIT { 0.00102838f, 0.00759876f, 0.03600077f, 0.10936069f, \
                  0.21300553f, 0.26601172f, 0.21300553f, 0.10936069f, \
                  0.03600077f, 0.00759876f, 0.00102838f }

// NOTE: no 2nd launch_bounds arg. R1=(512,4) measured ~13.4 waves/CU,
// R3=(512,2) measured ~7.4 waves/CU with identical LDS/VGPR static limits —
// the min-waves-per-EU attribute is acting as an effective residency cap.
__global__ __launch_bounds__(512)
void ssim_main(const float* __restrict__ pred, const float* __restrict__ targ,
               double* __restrict__ acc) {
    const float WG[11] = WG_INIT;

    // 5 maps x 2 row-pair slots x (8 pad | 512 data | 8 pad) cols x 2 rows/pair
    // float2-interleaved: horizontal taps are packed across the row pair.
    __shared__ __align__(16) float lds[5][2][528 * 2];
    __shared__ float wsum[8];

    const int tid   = threadIdx.x;
    const int x     = tid;                 // column owned in vertical pass
    const int plane = blockIdx.y;
    const int y0    = blockIdx.x * TY;
    const size_t base = (size_t)plane * (IMG_W * IMG_H);
    const float* pCol = pred + base + x;
    const float* tCol = targ + base + x;

    // Zero horizontal halo pads (cols 0..7 and 520..527); data writes never
    // touch them. Single phase -> single barrier covers both pad+data writes.
    if (tid < 160) {
        int m   = tid >> 5;           // 0..4
        int rem = tid & 31;
        int rl  = rem >> 4;           // 0..1
        int cc  = rem & 15;           // 0..15
        int c   = (cc < 8) ? cc : (512 + cc);
        *(f32x2*)&lds[m][rl][2 * c] = (f32x2){0.f, 0.f};
    }

    // ---- vertical pass: 14 input rows -> 4 output rows as 2 packed pairs ----
    // All 28 loads issued before any consuming FMA: max memory-level parallelism.
    float pv[TY + 10], tv[TY + 10];
#pragma unroll
    for (int iy = 0; iy < TY + 10; ++iy) {
        int y = y0 - 5 + iy;
        pv[iy] = 0.f; tv[iy] = 0.f;
        if ((unsigned)y < (unsigned)IMG_H) {   // wave-uniform
            pv[iy] = pCol[(size_t)y * IMG_W];
            tv[iy] = tCol[(size_t)y * IMG_W];
        }
    }

    f32x2 A[5][2];
#pragma unroll
    for (int m = 0; m < 5; ++m) { A[m][0] = (f32x2){0.f, 0.f}; A[m][1] = (f32x2){0.f, 0.f}; }

#pragma unroll
    for (int iy = 0; iy < TY + 10; ++iy) {
        const float p = pv[iy], t = tv[iy];
        const float pp = p * p, tt = t * t, pt = p * t;
        const f32x2 vs[5] = { {p, p}, {t, t}, {pp, pp}, {tt, tt}, {pt, pt} };
#pragma unroll
        for (int rp = 0; rp < 2; ++rp) {
            const int a = iy - 2 * rp;                      // compile-time
            if (a < 0 || a > 11) continue;                  // both lanes zero
            const float w0 = (a <= 10) ? WG[a] : 0.f;       // row 2rp
            const float w1 = (a >= 1)  ? WG[a - 1] : 0.f;   // row 2rp+1
            const f32x2 w = (f32x2){w0, w1};
#pragma unroll
            for (int m = 0; m < 5; ++m)
                A[m][rp] = __builtin_elementwise_fma(vs[m], w, A[m][rp]);
        }
    }

#pragma unroll
    for (int m = 0; m < 5; ++m) {
        *(f32x2*)&lds[m][0][2 * (x + 8)] = A[m][0];
        *(f32x2*)&lds[m][1][2 * (x + 8)] = A[m][1];
    }
    __syncthreads();

    // ---- horizontal pass + SSIM ----
    const float C1 = 1e-4f, C2 = 9e-4f;
    float lsum = 0.f;
    const int rpl = tid >> 8;          // 0..1: row pair this thread processes
    const int xq  = (tid & 255) * 2;   // first of 2 output cols (even)

    // out col j taps stored entries j+3..j+13; cols (xq, xq+1) need entries
    // xq+3..xq+14; read aligned window xq+2..xq+15 (7 x ds_read_b128).
    f32x2 H[5][2];
#pragma unroll
    for (int m = 0; m < 5; ++m) {
        f32x2 win[14];
#pragma unroll
        for (int q = 0; q < 7; ++q) {
            const float4 v = *(const float4*)&lds[m][rpl][2 * (xq + 2) + 4 * q];
            win[2 * q]     = (f32x2){v.x, v.y};
            win[2 * q + 1] = (f32x2){v.z, v.w};
        }
        f32x2 h0 = (f32x2){0.f, 0.f}, h1 = (f32x2){0.f, 0.f};
#pragma unroll
        for (int k = 0; k < 11; ++k) {
            const f32x2 wk = (f32x2){WG[k], WG[k]};
            h0 = __builtin_elementwise_fma(win[1 + k], wk, h0);
            h1 = __builtin_elementwise_fma(win[2 + k], wk, h1);
        }
        H[m][0] = h0; H[m][1] = h1;
    }

#pragma unroll
    for (int c = 0; c < 2; ++c) {
        f32x2 mu1 = H[0][c], mu2 = H[1][c];
        f32x2 mu1s = mu1 * mu1, mu2s = mu2 * mu2, mu12 = mu1 * mu2;
        f32x2 s1  = H[2][c] - mu1s;
        f32x2 s2  = H[3][c] - mu2s;
        f32x2 s12 = H[4][c] - mu12;
        f32x2 num = (mu12 + mu12 + (f32x2){C1, C1}) *
                    (s12 + s12 + (f32x2){C2, C2});
        f32x2 den = (mu1s + mu2s + (f32x2){C1, C1}) *
                    (s1 + s2 + (f32x2){C2, C2}) + (f32x2){1e-8f, 1e-8f};
        lsum += num.x * __builtin_amdgcn_rcpf(den.x);
        lsum += num.y * __builtin_amdgcn_rcpf(den.y);
    }

    // ---- reduction: wave shuffle -> LDS -> one double atomic per block ----
#pragma unroll
    for (int off = 32; off > 0; off >>= 1)
        lsum += __shfl_down(lsum, off);
    if ((tid & 63) == 0) wsum[tid >> 6] = lsum;
    __syncthreads();
    if (tid == 0) {
        float s = 0.f;
#pragma unroll
        for (int i = 0; i < 8; ++i) s += wsum[i];
        atomicAdd(acc, (double)s);
    }
}

__global__ void ssim_final(const double* __restrict__ acc, float* __restrict__ out) {
    out[0] = 1.0f - (float)(acc[0] * (1.0 / (double)NPIX));
}

extern "C" void kernel_launch(void* const* d_in, const int* in_sizes, int n_in,
                              void* d_out, int out_size, void* d_ws, size_t ws_size,
                              hipStream_t stream) {
    const float* pred = (const float*)d_in[0];
    const float* targ = (const float*)d_in[1];
    double* acc = (double*)d_ws;

    hipMemsetAsync(acc, 0, sizeof(double), stream);

    dim3 grid(IMG_H / TY, PLANES);   // adjacent strips -> halo L2/L3 reuse
    ssim_main<<<grid, 512, 0, stream>>>(pred, targ, acc);
    ssim_final<<<1, 1, 0, stream>>>(acc, (float*)d_out);
}